// Round 8
// baseline (2096.569 us; speedup 1.0000x reference)
//
#include <hip/hip_runtime.h>
#include <float.h>
#include <limits.h>

#define NROWS 16384
#define NE    8192
#define DIM   512

// ---- fast pass geometry ----
#define TMF 128
#define TNF 128
#define NSPLITF 4
#define NRANGE (NE / NSPLITF)   // 2048
#define LDK 40                  // padded LDS k-stride (ushorts): 80B rows

// ---- workspace layout (bytes) ----
#define WS_PM1  0               // float[NROWS*4]  (reused as refine partial d)
#define WS_PM2  262144          // float[NROWS*4]
#define WS_PI1  524288          // int[NROWS*4]    (reused as refine partial n)
#define WS_FIDX 786432          // int[NROWS]
#define WS_LIST 851968          // int[NROWS]
#define WS_CNT  917504          // int
// optional e-presplit region (used only if ws_size large enough)
#define WS_EH   1048576         // ushort[NE*DIM] = 8 MB
#define WS_EL   9437184         // ushort[NE*DIM] = 8 MB
#define WS_NEED_E 17825792

typedef __bf16 bf16x8 __attribute__((ext_vector_type(8)));
typedef unsigned short u16x4 __attribute__((ext_vector_type(4)));
typedef unsigned short u16x8 __attribute__((ext_vector_type(8)));
typedef float f32x4v __attribute__((ext_vector_type(4)));

__device__ __forceinline__ unsigned int bf16rne(float f) {
  unsigned int u = __float_as_uint(f);
  return (u + 0x7FFFu + ((u >> 16) & 1u)) >> 16;
}
// f = f32(hi<<16) + f32(lo<<16) + delta, |delta| <= 2^-18 |f|
__device__ __forceinline__ void split2(float f, unsigned short& h, unsigned short& l) {
  unsigned int hb = bf16rne(f);
  h = (unsigned short)hb;
  float rem = f - __uint_as_float(hb << 16);
  l = (unsigned short)bf16rne(rem);
}

// ---------------- K0: elementwise bf16 hi/lo pre-split ----------------
// 8 elements (2 float4) per thread
__global__ void k_presplit(const float* __restrict__ src,
                           unsigned short* __restrict__ hi,
                           unsigned short* __restrict__ lo) {
  size_t i8 = (size_t)blockIdx.x * 256 + threadIdx.x;   // index of 8-elem group
  const float4* s4 = (const float4*)src;
  float4 a = s4[i8 * 2], b = s4[i8 * 2 + 1];
  unsigned short h[8], l[8];
  split2(a.x, h[0], l[0]); split2(a.y, h[1], l[1]);
  split2(a.z, h[2], l[2]); split2(a.w, h[3], l[3]);
  split2(b.x, h[4], l[4]); split2(b.y, h[5], l[5]);
  split2(b.z, h[6], l[6]); split2(b.w, h[7], l[7]);
  *(u16x8*)(hi + i8 * 8) = (u16x8){h[0],h[1],h[2],h[3],h[4],h[5],h[6],h[7]};
  *(u16x8*)(lo + i8 * 8) = (u16x8){l[0],l[1],l[2],l[3],l[4],l[5],l[6],l[7]};
}

// ---------------- K1: MFMA (Markidis split-bf16) GEMM-max over G = z.e ----------------
// grid (NROWS/TMF, NSPLITF), block 512 = 8 waves (4m x 2n), wave tile 32x64
template<bool PRE_E>
__global__ __launch_bounds__(512, 4) void k_fastm(
    const unsigned short* __restrict__ zh, const unsigned short* __restrict__ zl,
    const float* __restrict__ cb,
    const unsigned short* __restrict__ eh, const unsigned short* __restrict__ el,
    float* __restrict__ pm1, float* __restrict__ pm2, int* __restrict__ pi1,
    int* __restrict__ counter) {
  __shared__ unsigned short zh_t[TMF][LDK], zl_t[TMF][LDK];   // 10240 B each
  __shared__ unsigned short eh_t[TNF][LDK], el_t[TNF][LDK];
  __shared__ float redm1[TMF][2], redm2[TMF][2];
  __shared__ int   redi1[TMF][2];

  const int t    = threadIdx.x;
  const int lane = t & 63, w = t >> 6;
  const int wm   = w >> 1, wn = w & 1;      // 4 m-stripes x 2 n-halves
  const int lr   = lane & 15, lg = lane >> 4;
  const int mBase  = blockIdx.x * TMF;
  const int nBase0 = blockIdx.y * NRANGE;
  if (blockIdx.x == 0 && blockIdx.y == 0 && t == 0) *counter = 0;

  float m1[8], m2[8]; int i1[8];
  #pragma unroll
  for (int s = 0; s < 8; ++s) { m1[s] = -FLT_MAX; m2[s] = -FLT_MAX; i1[s] = INT_MAX; }

  for (int nt = 0; nt < NRANGE / TNF; ++nt) {   // 16 n-tiles
    const int nB = nBase0 + nt * TNF;
    f32x4v acc[2][4];
    #pragma unroll
    for (int mi = 0; mi < 2; ++mi)
      #pragma unroll
      for (int nj = 0; nj < 4; ++nj) acc[mi][nj] = (f32x4v){0.f, 0.f, 0.f, 0.f};

    for (int ks = 0; ks < DIM / 32; ++ks) {     // 16 K-steps of 32
      const int kc = ks * 32;
      __syncthreads();                          // prior reads done before overwrite
      // stage z slab 128x32 from pre-split hi/lo: 512 16B-chunks, 1/thread each
      {
        int row = t >> 2, q = t & 3;
        size_t off = (size_t)(mBase + row) * DIM + kc + q * 8;
        *(u16x8*)&zh_t[row][q * 8] = *(const u16x8*)(zh + off);
        *(u16x8*)&zl_t[row][q * 8] = *(const u16x8*)(zl + off);
      }
      if (PRE_E) {
        int row = t >> 2, q = t & 3;
        size_t off = (size_t)(nB + row) * DIM + kc + q * 8;
        *(u16x8*)&eh_t[row][q * 8] = *(const u16x8*)(eh + off);
        *(u16x8*)&el_t[row][q * 8] = *(const u16x8*)(el + off);
      } else {
        #pragma unroll
        for (int i = 0; i < 2; ++i) {
          int li = t + i * 512, row = li >> 3, q = li & 7;
          float4 v = *(const float4*)(cb + (size_t)(nB + row) * DIM + kc + q * 4);
          unsigned short h0,h1,h2,h3,l0,l1,l2,l3;
          split2(v.x,h0,l0); split2(v.y,h1,l1); split2(v.z,h2,l2); split2(v.w,h3,l3);
          *(u16x4*)&eh_t[row][q*4] = (u16x4){h0,h1,h2,h3};
          *(u16x4*)&el_t[row][q*4] = (u16x4){l0,l1,l2,l3};
        }
      }
      __syncthreads();

      bf16x8 ah[2], al[2];
      #pragma unroll
      for (int mi = 0; mi < 2; ++mi) {
        int row = wm * 32 + mi * 16 + lr;
        ah[mi] = *(const bf16x8*)&zh_t[row][lg * 8];
        al[mi] = *(const bf16x8*)&zl_t[row][lg * 8];
      }
      #pragma unroll
      for (int nj = 0; nj < 4; ++nj) {
        int erow = wn * 64 + nj * 16 + lr;
        bf16x8 bh = *(const bf16x8*)&eh_t[erow][lg * 8];
        bf16x8 bl = *(const bf16x8*)&el_t[erow][lg * 8];
        #pragma unroll
        for (int mi = 0; mi < 2; ++mi) {
          acc[mi][nj] = __builtin_amdgcn_mfma_f32_16x16x32_bf16(ah[mi], bh, acc[mi][nj], 0, 0, 0);
          acc[mi][nj] = __builtin_amdgcn_mfma_f32_16x16x32_bf16(ah[mi], bl, acc[mi][nj], 0, 0, 0);
          acc[mi][nj] = __builtin_amdgcn_mfma_f32_16x16x32_bf16(al[mi], bh, acc[mi][nj], 0, 0, 0);
        }
      }
    }
    // fold: lane col = wn*64 + nj*16 + lr, row-slot s = mi*4+reg; n ascending (nt,nj)
    #pragma unroll
    for (int nj = 0; nj < 4; ++nj) {
      int n = nB + wn * 64 + nj * 16 + lr;
      #pragma unroll
      for (int mi = 0; mi < 2; ++mi)
        #pragma unroll
        for (int r = 0; r < 4; ++r) {
          float v = acc[mi][nj][r];
          int s = mi * 4 + r;
          if (v > m1[s]) { m2[s] = m1[s]; m1[s] = v; i1[s] = n; }
          else if (v > m2[s]) m2[s] = v;
        }
    }
  }

  // butterfly top-2 merge across the 16 col-lanes
  #pragma unroll
  for (int off = 1; off <= 8; off <<= 1) {
    #pragma unroll
    for (int s = 0; s < 8; ++s) {
      float om1 = __shfl_xor(m1[s], off);
      float om2 = __shfl_xor(m2[s], off);
      int   oi  = __shfl_xor(i1[s], off);
      if (om1 > m1[s] || (om1 == m1[s] && oi < i1[s])) {
        m2[s] = fmaxf(m1[s], om2); m1[s] = om1; i1[s] = oi;
      } else {
        m2[s] = fmaxf(m2[s], om1);
      }
    }
  }
  if (lr == 0) {
    #pragma unroll
    for (int s = 0; s < 8; ++s) {
      int row = wm * 32 + (s >> 2) * 16 + lg * 4 + (s & 3);
      redm1[row][wn] = m1[s]; redm2[row][wn] = m2[s]; redi1[row][wn] = i1[s];
    }
  }
  __syncthreads();
  if (t < TMF) {
    float M1 = redm1[t][0], M2 = redm2[t][0]; int I1 = redi1[t][0];
    float a1 = redm1[t][1], a2 = redm2[t][1]; int ai = redi1[t][1];
    if (a1 > M1 || (a1 == M1 && ai < I1)) { M2 = fmaxf(M1, a2); M1 = a1; I1 = ai; }
    else M2 = fmaxf(M2, a1);
    size_t gm = (size_t)(mBase + t);
    pm1[gm * NSPLITF + blockIdx.y] = M1;
    pm2[gm * NSPLITF + blockIdx.y] = M2;
    pi1[gm * NSPLITF + blockIdx.y] = I1;
  }
}

// ---------------- K2: merge splits, compute A, flag near-ties ----------------
__global__ void k_merge(const float* __restrict__ z,
                        const float* __restrict__ pm1, const float* __restrict__ pm2,
                        const int* __restrict__ pi1,
                        int* __restrict__ fidx, int* __restrict__ list,
                        int* __restrict__ counter) {
  int m = blockIdx.x * 256 + threadIdx.x;
  float M1 = -FLT_MAX, M2 = -FLT_MAX; int I1 = INT_MAX;
  #pragma unroll
  for (int s = 0; s < NSPLITF; ++s) {
    float a1 = pm1[(size_t)m * NSPLITF + s], a2 = pm2[(size_t)m * NSPLITF + s];
    int   ai = pi1[(size_t)m * NSPLITF + s];
    if (a1 > M1 || (a1 == M1 && ai < I1)) { M2 = fmaxf(M1, a2); M1 = a1; I1 = ai; }
    else M2 = fmaxf(M2, a1);
  }
  double A = 0.0;
  const float4* zr = (const float4*)(z + (size_t)m * DIM);
  for (int q = 0; q < DIM / 4; ++q) {
    float4 v = zr[q];
    A += (double)v.x * v.x + (double)v.y * v.y + (double)v.z * v.z + (double)v.w * v.w;
  }
  float A32 = (float)A;
  // unflagged => G-gap > 0.5*ulp(d) + 2*eta. 0.75u + 3.5e-6 (Markidis eta <= ~1e-6)
  float u   = (A32 > 511.8f) ? 6.1035156e-5f : 3.0517578e-5f;
  float tau = 0.75f * u + 3.5e-6f;
  fidx[m] = I1;
  if (M1 - M2 < tau) { int p = atomicAdd(counter, 1); list[p] = m; }
}

// ---------------- K3: exact npyv rescan, 8 rows x 4 n-splits, 4x4 thread tile ----------------
__global__ __launch_bounds__(256) void k_refine2(
    const float* __restrict__ z, const float* __restrict__ cb,
    const int* __restrict__ list, const int* __restrict__ counter,
    float* __restrict__ rd, int* __restrict__ rn) {
  __shared__ __align__(16) float zs2[8][516];
  __shared__ float est[16][516];
  __shared__ double apart[8][16];
  __shared__ float Arow[8];
  __shared__ int mrow[8];
  __shared__ float rdm[8][128];
  __shared__ int rnm[8][128];

  const int cnt = *counter;
  const int gB = blockIdx.x * 8;
  if (gB >= cnt) return;
  const int t = threadIdx.x;
  const int split = blockIdx.y;
  const int nBase0 = split * (NE / 4);
  const int rg = t >> 7, cg = t & 127;

  if (t < 8) mrow[t] = list[(gB + t < cnt) ? gB + t : cnt - 1];
  __syncthreads();
  #pragma unroll
  for (int i = 0; i < 4; ++i) {
    int li = t + 256 * i; int r = li >> 7, q = li & 127;
    *(float4*)&zs2[r][q * 4] = *(const float4*)(z + (size_t)mrow[r] * DIM + q * 4);
  }
  __syncthreads();
  if (t < 128) {
    int r = t >> 4, seg = t & 15;
    double s = 0.0;
    for (int k = seg * 32; k < seg * 32 + 32; ++k) { double v = zs2[r][k]; s += v * v; }
    apart[r][seg] = s;
  }
  __syncthreads();
  if (t < 8) { double s = 0.0; for (int c2 = 0; c2 < 16; ++c2) s += apart[t][c2]; Arow[t] = (float)s; }
  __syncthreads();

  float bd[4] = {FLT_MAX, FLT_MAX, FLT_MAX, FLT_MAX};
  int   bn[4] = {INT_MAX, INT_MAX, INT_MAX, INT_MAX};

  for (int tile = 0; tile < 4; ++tile) {
    const int colBase = nBase0 + tile * 512;
    float L[4][4][4];
    #pragma unroll
    for (int r = 0; r < 4; ++r)
      #pragma unroll
      for (int cj = 0; cj < 4; ++cj)
        #pragma unroll
        for (int j = 0; j < 4; ++j) L[r][cj][j] = 0.0f;

    for (int kc = 0; kc < DIM; kc += 16) {
      __syncthreads();
      #pragma unroll
      for (int i = 0; i < 8; ++i) {
        int li = t + 256 * i; int col = li >> 2, q = li & 3;
        float4 v = *(const float4*)(cb + (size_t)(colBase + col) * DIM + kc + 4 * q);
        est[4*q+0][col] = v.x; est[4*q+1][col] = v.y;
        est[4*q+2][col] = v.z; est[4*q+3][col] = v.w;
      }
      __syncthreads();
      #pragma unroll
      for (int sub = 3; sub >= 0; --sub) {
        float zb[4][4], eb[4][4];
        #pragma unroll
        for (int r = 0; r < 4; ++r)
          #pragma unroll
          for (int j = 0; j < 4; ++j)
            zb[r][j] = zs2[rg * 4 + r][kc + 4 * sub + j];
        #pragma unroll
        for (int cj = 0; cj < 4; ++cj)
          #pragma unroll
          for (int j = 0; j < 4; ++j)
            eb[cj][j] = est[4 * sub + j][cg + 128 * cj];
        #pragma unroll
        for (int r = 0; r < 4; ++r)
          #pragma unroll
          for (int cj = 0; cj < 4; ++cj)
            #pragma unroll
            for (int j = 0; j < 4; ++j)
              L[r][cj][j] = __fadd_rn(L[r][cj][j], __fmul_rn(zb[r][j], eb[cj][j]));
      }
    }
    #pragma unroll
    for (int cj = 0; cj < 4; ++cj)
      #pragma unroll
      for (int r = 0; r < 4; ++r) {
        float G = __fadd_rn(__fadd_rn(L[r][cj][0], L[r][cj][1]),
                            __fadd_rn(L[r][cj][2], L[r][cj][3]));
        float d = __fsub_rn(Arow[rg * 4 + r], __fmul_rn(2.0f, G));
        int n = colBase + cg + 128 * cj;
        if (d < bd[r] || (d == bd[r] && n < bn[r])) { bd[r] = d; bn[r] = n; }
      }
  }
  __syncthreads();
  #pragma unroll
  for (int r = 0; r < 4; ++r) { rdm[rg*4+r][cg] = bd[r]; rnm[rg*4+r][cg] = bn[r]; }
  __syncthreads();
  if (t < 8) {
    float fb = FLT_MAX; int fn = INT_MAX;
    for (int c2 = 0; c2 < 128; ++c2) {
      float d = rdm[t][c2]; int n = rnm[t][c2];
      if (d < fb || (d == fb && n < fn)) { fb = d; fn = n; }
    }
    if (gB + t < cnt) {
      int m = mrow[t];
      rd[(size_t)m * 4 + split] = fb;
      rn[(size_t)m * 4 + split] = fn;
    }
  }
}

// ---------------- K3b: merge refine splits ----------------
__global__ void k_fmerge(const int* __restrict__ list, const int* __restrict__ counter,
                         const float* __restrict__ rd, const int* __restrict__ rn,
                         int* __restrict__ fidx) {
  int i = blockIdx.x * 256 + threadIdx.x;
  if (i >= *counter) return;
  int m = list[i];
  float fb = FLT_MAX; int fn = INT_MAX;
  #pragma unroll
  for (int s = 0; s < 4; ++s) {
    float d = rd[(size_t)m * 4 + s]; int n = rn[(size_t)m * 4 + s];
    if (d < fb || (d == fb && n < fn)) { fb = d; fn = n; }
  }
  fidx[m] = fn;
}

// ---------------- K4: gather z_q + index floats (fully rewrites d_out) ----------------
__global__ void k_gather(const float* __restrict__ cb, const int* __restrict__ fidx,
                         float* __restrict__ out) {
  __shared__ int idxs[32];
  const int t = threadIdx.x;
  const int mBase = blockIdx.x * 32;
  if (t < 32) {
    int id = fidx[mBase + t];
    idxs[t] = id;
    out[(size_t)NROWS * DIM + mBase + t] = (float)id;
  }
  __syncthreads();
  #pragma unroll
  for (int i = 0; i < 16; ++i) {
    int li = t + i * 256, r = li >> 7, q = li & 127;
    *(float4*)(out + (size_t)(mBase + r) * DIM + q * 4) =
        *(const float4*)(cb + (size_t)idxs[r] * DIM + q * 4);
  }
}

extern "C" void kernel_launch(void* const* d_in, const int* in_sizes, int n_in,
                              void* d_out, int out_size, void* d_ws, size_t ws_size,
                              hipStream_t stream) {
  const float* z  = (const float*)d_in[0];
  const float* cb = (const float*)d_in[1];
  float* out = (float*)d_out;
  char* ws = (char*)d_ws;
  float* pm1 = (float*)(ws + WS_PM1);
  float* pm2 = (float*)(ws + WS_PM2);
  int*   pi1 = (int*)(ws + WS_PI1);
  int*   fidx = (int*)(ws + WS_FIDX);
  int*   list = (int*)(ws + WS_LIST);
  int*   cnt  = (int*)(ws + WS_CNT);

  // z hi/lo pre-split lives in d_out (33,554,432 B <= 33,619,968 B);
  // k_gather fully rewrites d_out afterward (stream-ordered).
  unsigned short* zh = (unsigned short*)d_out;
  unsigned short* zl = zh + (size_t)NROWS * DIM;

  hipLaunchKernelGGL(k_presplit, dim3(NROWS * DIM / (256 * 8)), dim3(256), 0, stream,
                     z, zh, zl);

  const bool pre_e = (ws_size >= (size_t)WS_NEED_E);
  unsigned short* eh = (unsigned short*)(ws + WS_EH);
  unsigned short* el = (unsigned short*)(ws + WS_EL);
  if (pre_e) {
    hipLaunchKernelGGL(k_presplit, dim3(NE * DIM / (256 * 8)), dim3(256), 0, stream,
                       cb, eh, el);
    hipLaunchKernelGGL(k_fastm<true>, dim3(NROWS / TMF, NSPLITF), dim3(512), 0, stream,
                       zh, zl, cb, eh, el, pm1, pm2, pi1, cnt);
  } else {
    hipLaunchKernelGGL(k_fastm<false>, dim3(NROWS / TMF, NSPLITF), dim3(512), 0, stream,
                       zh, zl, cb, eh, el, pm1, pm2, pi1, cnt);
  }

  hipLaunchKernelGGL(k_merge,   dim3(NROWS / 256), dim3(256), 0, stream,
                     z, pm1, pm2, pi1, fidx, list, cnt);
  hipLaunchKernelGGL(k_refine2, dim3(NROWS / 8, 4), dim3(256), 0, stream,
                     z, cb, list, cnt, pm1, pi1);
  hipLaunchKernelGGL(k_fmerge,  dim3(NROWS / 256), dim3(256), 0, stream,
                     list, cnt, pm1, pi1, fidx);
  hipLaunchKernelGGL(k_gather,  dim3(NROWS / 32), dim3(256), 0, stream,
                     cb, fidx, out);
}

// Round 9
// 1483.928 us; speedup vs baseline: 1.4129x; 1.4129x over previous
//
#include <hip/hip_runtime.h>
#include <float.h>
#include <limits.h>

#define NROWS 16384
#define NE    8192
#define DIM   512

// ---- fast pass geometry ----
#define TMF 128
#define TNF 128
#define NSPLITF 4
#define NRANGE (NE / NSPLITF)   // 2048

// ---- workspace layout (bytes) ----
#define WS_PM1  0               // float[NROWS*4]  (reused as refine partial d)
#define WS_PM2  262144          // float[NROWS*4]
#define WS_PI1  524288          // int[NROWS*4]    (reused as refine partial n)
#define WS_FIDX 786432          // int[NROWS]
#define WS_LIST 851968          // int[NROWS]
#define WS_CNT  917504          // int
#define WS_EH   1048576         // ushort[NE*DIM] = 8 MB
#define WS_EL   9437184         // ushort[NE*DIM] = 8 MB
#define WS_NEED_E 17825792

typedef __bf16 bf16x8 __attribute__((ext_vector_type(8)));
typedef unsigned short u16x8 __attribute__((ext_vector_type(8)));
typedef float f32x4v __attribute__((ext_vector_type(4)));

__device__ __forceinline__ unsigned int bf16rne(float f) {
  unsigned int u = __float_as_uint(f);
  return (u + 0x7FFFu + ((u >> 16) & 1u)) >> 16;
}
__device__ __forceinline__ void split2(float f, unsigned short& h, unsigned short& l) {
  unsigned int hb = bf16rne(f);
  h = (unsigned short)hb;
  float rem = f - __uint_as_float(hb << 16);
  l = (unsigned short)bf16rne(rem);
}

// async 16B global -> LDS (linear dest: wave-uniform base + lane*16)
typedef __attribute__((address_space(1))) const void GV;
typedef __attribute__((address_space(3))) void LV;
__device__ __forceinline__ void gload16(const void* g, void* l) {
  __builtin_amdgcn_global_load_lds((GV*)g, (LV*)l, 16, 0, 0);
}

// ---------------- K0: elementwise bf16 hi/lo pre-split ----------------
__global__ void k_presplit(const float* __restrict__ src,
                           unsigned short* __restrict__ hi,
                           unsigned short* __restrict__ lo) {
  size_t i8 = (size_t)blockIdx.x * 256 + threadIdx.x;
  const float4* s4 = (const float4*)src;
  float4 a = s4[i8 * 2], b = s4[i8 * 2 + 1];
  unsigned short h[8], l[8];
  split2(a.x, h[0], l[0]); split2(a.y, h[1], l[1]);
  split2(a.z, h[2], l[2]); split2(a.w, h[3], l[3]);
  split2(b.x, h[4], l[4]); split2(b.y, h[5], l[5]);
  split2(b.z, h[6], l[6]); split2(b.w, h[7], l[7]);
  *(u16x8*)(hi + i8 * 8) = (u16x8){h[0],h[1],h[2],h[3],h[4],h[5],h[6],h[7]};
  *(u16x8*)(lo + i8 * 8) = (u16x8){l[0],l[1],l[2],l[3],l[4],l[5],l[6],l[7]};
}

// ---------------- K1: MFMA GEMM-max, dbuf + global_load_lds + swizzled LDS ----------------
// grid (NROWS/TMF, NSPLITF), block 512 = 8 waves (4m x 2n), wave tile 32x64.
// LDS tile: [row][32k] ushort, 64B rows, 4 slots of 16B; phys_slot = log_slot ^ ((row>>1)&3).
// Staging: linear LDS dest (global_load_lds), inverse-swizzled global source (rule #21).
__global__ __launch_bounds__(512, 4) void k_fastm(
    const unsigned short* __restrict__ zh, const unsigned short* __restrict__ zl,
    const unsigned short* __restrict__ eh, const unsigned short* __restrict__ el,
    float* __restrict__ pm1, float* __restrict__ pm2, int* __restrict__ pi1,
    int* __restrict__ counter) {
  __shared__ unsigned short buf[2][4][TMF][32];   // [dbuf][zh,zl,eh,el][row][k] = 64 KB
  __shared__ float redm1[TMF][2], redm2[TMF][2];
  __shared__ int   redi1[TMF][2];

  const int t    = threadIdx.x;
  const int lane = t & 63, w = t >> 6;
  const int wm   = w >> 1, wn = w & 1;
  const int lr   = lane & 15, lg = lane >> 4;
  const int mBase  = blockIdx.x * TMF;
  const int nBase0 = blockIdx.y * NRANGE;
  if (blockIdx.x == 0 && blockIdx.y == 0 && t == 0) *counter = 0;

  // staging lane map (constant per thread): wave w stages rows 16w..16w+15 of each tile
  const int srow = (w << 4) + (lane >> 2);            // local row
  const int sslot = (lane & 3) ^ ((srow >> 1) & 3);   // inverse-swizzled logical slot
  const size_t zrowoff = (size_t)(mBase + srow) * DIM + sslot * 8;

  float m1[8], m2[8]; int i1[8];
  #pragma unroll
  for (int s = 0; s < 8; ++s) { m1[s] = -FLT_MAX; m2[s] = -FLT_MAX; i1[s] = INT_MAX; }

  // prologue: stage step 0 into buffer 0
  {
    gload16(zh + zrowoff, &buf[0][0][w << 4][0]);
    gload16(zl + zrowoff, &buf[0][1][w << 4][0]);
    size_t eoff = (size_t)(nBase0 + srow) * DIM + sslot * 8;
    gload16(eh + eoff, &buf[0][2][w << 4][0]);
    gload16(el + eoff, &buf[0][3][w << 4][0]);
  }
  __syncthreads();

  int cur = 0;
  for (int nt = 0; nt < NRANGE / TNF; ++nt) {     // 16 n-tiles
    const int nB = nBase0 + nt * TNF;
    f32x4v acc[2][4];
    #pragma unroll
    for (int mi = 0; mi < 2; ++mi)
      #pragma unroll
      for (int nj = 0; nj < 4; ++nj) acc[mi][nj] = (f32x4v){0.f, 0.f, 0.f, 0.f};

    for (int ks = 0; ks < 16; ++ks) {             // 16 K-steps of 32
      // ---- stage next step into buf[cur^1] (async, hides under MFMA) ----
      int s = nt * 16 + ks;
      if (s + 1 < 256) {
        int s2 = s + 1, nt2 = s2 >> 4, ks2 = s2 & 15;
        size_t zo = zrowoff + ks2 * 32;
        size_t eo = (size_t)(nBase0 + nt2 * TNF + srow) * DIM + ks2 * 32 + sslot * 8;
        gload16(zh + zo, &buf[cur ^ 1][0][w << 4][0]);
        gload16(zl + zo, &buf[cur ^ 1][1][w << 4][0]);
        gload16(eh + eo, &buf[cur ^ 1][2][w << 4][0]);
        gload16(el + eo, &buf[cur ^ 1][3][w << 4][0]);
      }
      // ---- compute on buf[cur] (swizzled fragment reads) ----
      bf16x8 ah[2], al[2];
      #pragma unroll
      for (int mi = 0; mi < 2; ++mi) {
        int row = wm * 32 + mi * 16 + lr;
        int sl  = (lg ^ ((row >> 1) & 3)) * 8;
        ah[mi] = *(const bf16x8*)&buf[cur][0][row][sl];
        al[mi] = *(const bf16x8*)&buf[cur][1][row][sl];
      }
      #pragma unroll
      for (int nj = 0; nj < 4; ++nj) {
        int erow = wn * 64 + nj * 16 + lr;
        int esl  = (lg ^ ((erow >> 1) & 3)) * 8;
        bf16x8 bh = *(const bf16x8*)&buf[cur][2][erow][esl];
        bf16x8 bl = *(const bf16x8*)&buf[cur][3][erow][esl];
        #pragma unroll
        for (int mi = 0; mi < 2; ++mi) {
          acc[mi][nj] = __builtin_amdgcn_mfma_f32_16x16x32_bf16(ah[mi], bh, acc[mi][nj], 0, 0, 0);
          acc[mi][nj] = __builtin_amdgcn_mfma_f32_16x16x32_bf16(ah[mi], bl, acc[mi][nj], 0, 0, 0);
          acc[mi][nj] = __builtin_amdgcn_mfma_f32_16x16x32_bf16(al[mi], bh, acc[mi][nj], 0, 0, 0);
        }
      }
      __syncthreads();          // drains vmcnt (stage done) + lgkm; buf[cur] reads done
      cur ^= 1;
    }
    // fold into per-thread top-2 (n ascending in (nt,nj) -> first-index kept)
    #pragma unroll
    for (int nj = 0; nj < 4; ++nj) {
      int n = nB + wn * 64 + nj * 16 + lr;
      #pragma unroll
      for (int mi = 0; mi < 2; ++mi)
        #pragma unroll
        for (int r = 0; r < 4; ++r) {
          float v = acc[mi][nj][r];
          int s = mi * 4 + r;
          if (v > m1[s]) { m2[s] = m1[s]; m1[s] = v; i1[s] = n; }
          else if (v > m2[s]) m2[s] = v;
        }
    }
  }

  // butterfly top-2 merge across the 16 col-lanes
  #pragma unroll
  for (int off = 1; off <= 8; off <<= 1) {
    #pragma unroll
    for (int s = 0; s < 8; ++s) {
      float om1 = __shfl_xor(m1[s], off);
      float om2 = __shfl_xor(m2[s], off);
      int   oi  = __shfl_xor(i1[s], off);
      if (om1 > m1[s] || (om1 == m1[s] && oi < i1[s])) {
        m2[s] = fmaxf(m1[s], om2); m1[s] = om1; i1[s] = oi;
      } else {
        m2[s] = fmaxf(m2[s], om1);
      }
    }
  }
  if (lr == 0) {
    #pragma unroll
    for (int s = 0; s < 8; ++s) {
      int row = wm * 32 + (s >> 2) * 16 + lg * 4 + (s & 3);
      redm1[row][wn] = m1[s]; redm2[row][wn] = m2[s]; redi1[row][wn] = i1[s];
    }
  }
  __syncthreads();
  if (t < TMF) {
    float M1 = redm1[t][0], M2 = redm2[t][0]; int I1 = redi1[t][0];
    float a1 = redm1[t][1], a2 = redm2[t][1]; int ai = redi1[t][1];
    if (a1 > M1 || (a1 == M1 && ai < I1)) { M2 = fmaxf(M1, a2); M1 = a1; I1 = ai; }
    else M2 = fmaxf(M2, a1);
    size_t gm = (size_t)(mBase + t);
    pm1[gm * NSPLITF + blockIdx.y] = M1;
    pm2[gm * NSPLITF + blockIdx.y] = M2;
    pi1[gm * NSPLITF + blockIdx.y] = I1;
  }
}

// ---------------- K2: merge splits, compute A, flag near-ties ----------------
__global__ void k_merge(const float* __restrict__ z,
                        const float* __restrict__ pm1, const float* __restrict__ pm2,
                        const int* __restrict__ pi1,
                        int* __restrict__ fidx, int* __restrict__ list,
                        int* __restrict__ counter) {
  int m = blockIdx.x * 256 + threadIdx.x;
  float M1 = -FLT_MAX, M2 = -FLT_MAX; int I1 = INT_MAX;
  #pragma unroll
  for (int s = 0; s < NSPLITF; ++s) {
    float a1 = pm1[(size_t)m * NSPLITF + s], a2 = pm2[(size_t)m * NSPLITF + s];
    int   ai = pi1[(size_t)m * NSPLITF + s];
    if (a1 > M1 || (a1 == M1 && ai < I1)) { M2 = fmaxf(M1, a2); M1 = a1; I1 = ai; }
    else M2 = fmaxf(M2, a1);
  }
  double A = 0.0;
  const float4* zr = (const float4*)(z + (size_t)m * DIM);
  for (int q = 0; q < DIM / 4; ++q) {
    float4 v = zr[q];
    A += (double)v.x * v.x + (double)v.y * v.y + (double)v.z * v.z + (double)v.w * v.w;
  }
  float A32 = (float)A;
  float u   = (A32 > 511.8f) ? 6.1035156e-5f : 3.0517578e-5f;
  float tau = 0.75f * u + 3.5e-6f;
  fidx[m] = I1;
  if (M1 - M2 < tau) { int p = atomicAdd(counter, 1); list[p] = m; }
}

// ---------------- K3: exact npyv rescan, 8 rows x 4 n-splits, 4x4 thread tile ----------------
__global__ __launch_bounds__(256) void k_refine2(
    const float* __restrict__ z, const float* __restrict__ cb,
    const int* __restrict__ list, const int* __restrict__ counter,
    float* __restrict__ rd, int* __restrict__ rn) {
  __shared__ __align__(16) float zs2[8][516];
  __shared__ float est[16][516];
  __shared__ double apart[8][16];
  __shared__ float Arow[8];
  __shared__ int mrow[8];
  __shared__ float rdm[8][128];
  __shared__ int rnm[8][128];

  const int cnt = *counter;
  const int gB = blockIdx.x * 8;
  if (gB >= cnt) return;
  const int t = threadIdx.x;
  const int split = blockIdx.y;
  const int nBase0 = split * (NE / 4);
  const int rg = t >> 7, cg = t & 127;

  if (t < 8) mrow[t] = list[(gB + t < cnt) ? gB + t : cnt - 1];
  __syncthreads();
  #pragma unroll
  for (int i = 0; i < 4; ++i) {
    int li = t + 256 * i; int r = li >> 7, q = li & 127;
    *(float4*)&zs2[r][q * 4] = *(const float4*)(z + (size_t)mrow[r] * DIM + q * 4);
  }
  __syncthreads();
  if (t < 128) {
    int r = t >> 4, seg = t & 15;
    double s = 0.0;
    for (int k = seg * 32; k < seg * 32 + 32; ++k) { double v = zs2[r][k]; s += v * v; }
    apart[r][seg] = s;
  }
  __syncthreads();
  if (t < 8) { double s = 0.0; for (int c2 = 0; c2 < 16; ++c2) s += apart[t][c2]; Arow[t] = (float)s; }
  __syncthreads();

  float bd[4] = {FLT_MAX, FLT_MAX, FLT_MAX, FLT_MAX};
  int   bn[4] = {INT_MAX, INT_MAX, INT_MAX, INT_MAX};

  for (int tile = 0; tile < 4; ++tile) {
    const int colBase = nBase0 + tile * 512;
    float L[4][4][4];
    #pragma unroll
    for (int r = 0; r < 4; ++r)
      #pragma unroll
      for (int cj = 0; cj < 4; ++cj)
        #pragma unroll
        for (int j = 0; j < 4; ++j) L[r][cj][j] = 0.0f;

    for (int kc = 0; kc < DIM; kc += 16) {
      __syncthreads();
      #pragma unroll
      for (int i = 0; i < 8; ++i) {
        int li = t + 256 * i; int col = li >> 2, q = li & 3;
        float4 v = *(const float4*)(cb + (size_t)(colBase + col) * DIM + kc + 4 * q);
        est[4*q+0][col] = v.x; est[4*q+1][col] = v.y;
        est[4*q+2][col] = v.z; est[4*q+3][col] = v.w;
      }
      __syncthreads();
      #pragma unroll
      for (int sub = 3; sub >= 0; --sub) {
        float zb[4][4], eb[4][4];
        #pragma unroll
        for (int r = 0; r < 4; ++r)
          #pragma unroll
          for (int j = 0; j < 4; ++j)
            zb[r][j] = zs2[rg * 4 + r][kc + 4 * sub + j];
        #pragma unroll
        for (int cj = 0; cj < 4; ++cj)
          #pragma unroll
          for (int j = 0; j < 4; ++j)
            eb[cj][j] = est[4 * sub + j][cg + 128 * cj];
        #pragma unroll
        for (int r = 0; r < 4; ++r)
          #pragma unroll
          for (int cj = 0; cj < 4; ++cj)
            #pragma unroll
            for (int j = 0; j < 4; ++j)
              L[r][cj][j] = __fadd_rn(L[r][cj][j], __fmul_rn(zb[r][j], eb[cj][j]));
      }
    }
    #pragma unroll
    for (int cj = 0; cj < 4; ++cj)
      #pragma unroll
      for (int r = 0; r < 4; ++r) {
        float G = __fadd_rn(__fadd_rn(L[r][cj][0], L[r][cj][1]),
                            __fadd_rn(L[r][cj][2], L[r][cj][3]));
        float d = __fsub_rn(Arow[rg * 4 + r], __fmul_rn(2.0f, G));
        int n = colBase + cg + 128 * cj;
        if (d < bd[r] || (d == bd[r] && n < bn[r])) { bd[r] = d; bn[r] = n; }
      }
  }
  __syncthreads();
  #pragma unroll
  for (int r = 0; r < 4; ++r) { rdm[rg*4+r][cg] = bd[r]; rnm[rg*4+r][cg] = bn[r]; }
  __syncthreads();
  if (t < 8) {
    float fb = FLT_MAX; int fn = INT_MAX;
    for (int c2 = 0; c2 < 128; ++c2) {
      float d = rdm[t][c2]; int n = rnm[t][c2];
      if (d < fb || (d == fb && n < fn)) { fb = d; fn = n; }
    }
    if (gB + t < cnt) {
      int m = mrow[t];
      rd[(size_t)m * 4 + split] = fb;
      rn[(size_t)m * 4 + split] = fn;
    }
  }
}

// ---------------- K3b: merge refine splits ----------------
__global__ void k_fmerge(const int* __restrict__ list, const int* __restrict__ counter,
                         const float* __restrict__ rd, const int* __restrict__ rn,
                         int* __restrict__ fidx) {
  int i = blockIdx.x * 256 + threadIdx.x;
  if (i >= *counter) return;
  int m = list[i];
  float fb = FLT_MAX; int fn = INT_MAX;
  #pragma unroll
  for (int s = 0; s < 4; ++s) {
    float d = rd[(size_t)m * 4 + s]; int n = rn[(size_t)m * 4 + s];
    if (d < fb || (d == fb && n < fn)) { fb = d; fn = n; }
  }
  fidx[m] = fn;
}

// ---------------- K4: gather z_q + index floats (fully rewrites d_out) ----------------
__global__ void k_gather(const float* __restrict__ cb, const int* __restrict__ fidx,
                         float* __restrict__ out) {
  __shared__ int idxs[32];
  const int t = threadIdx.x;
  const int mBase = blockIdx.x * 32;
  if (t < 32) {
    int id = fidx[mBase + t];
    idxs[t] = id;
    out[(size_t)NROWS * DIM + mBase + t] = (float)id;
  }
  __syncthreads();
  #pragma unroll
  for (int i = 0; i < 16; ++i) {
    int li = t + i * 256, r = li >> 7, q = li & 127;
    *(float4*)(out + (size_t)(mBase + r) * DIM + q * 4) =
        *(const float4*)(cb + (size_t)idxs[r] * DIM + q * 4);
  }
}

extern "C" void kernel_launch(void* const* d_in, const int* in_sizes, int n_in,
                              void* d_out, int out_size, void* d_ws, size_t ws_size,
                              hipStream_t stream) {
  const float* z  = (const float*)d_in[0];
  const float* cb = (const float*)d_in[1];
  float* out = (float*)d_out;
  char* ws = (char*)d_ws;
  float* pm1 = (float*)(ws + WS_PM1);
  float* pm2 = (float*)(ws + WS_PM2);
  int*   pi1 = (int*)(ws + WS_PI1);
  int*   fidx = (int*)(ws + WS_FIDX);
  int*   list = (int*)(ws + WS_LIST);
  int*   cnt  = (int*)(ws + WS_CNT);

  // z hi/lo pre-split lives in d_out (33,554,432 B <= out buffer);
  // k_gather fully rewrites d_out afterward (stream-ordered).
  unsigned short* zh = (unsigned short*)d_out;
  unsigned short* zl = zh + (size_t)NROWS * DIM;
  unsigned short* eh = (unsigned short*)(ws + WS_EH);
  unsigned short* el = (unsigned short*)(ws + WS_EL);

  hipLaunchKernelGGL(k_presplit, dim3(NROWS * DIM / (256 * 8)), dim3(256), 0, stream,
                     z, zh, zl);
  hipLaunchKernelGGL(k_presplit, dim3(NE * DIM / (256 * 8)), dim3(256), 0, stream,
                     cb, eh, el);
  hipLaunchKernelGGL(k_fastm,   dim3(NROWS / TMF, NSPLITF), dim3(512), 0, stream,
                     zh, zl, eh, el, pm1, pm2, pi1, cnt);
  hipLaunchKernelGGL(k_merge,   dim3(NROWS / 256), dim3(256), 0, stream,
                     z, pm1, pm2, pi1, fidx, list, cnt);
  hipLaunchKernelGGL(k_refine2, dim3(NROWS / 8, 4), dim3(256), 0, stream,
                     z, cb, list, cnt, pm1, pi1);
  hipLaunchKernelGGL(k_fmerge,  dim3(NROWS / 256), dim3(256), 0, stream,
                     list, cnt, pm1, pi1, fidx);
  hipLaunchKernelGGL(k_gather,  dim3(NROWS / 32), dim3(256), 0, stream,
                     cb, fidx, out);
}

// Round 10
// 983.727 us; speedup vs baseline: 2.1313x; 1.5085x over previous
//
#include <hip/hip_runtime.h>
#include <float.h>
#include <limits.h>

#define NROWS 16384
#define NE    8192
#define DIM   512

// ---- fast pass geometry ----
#define TMF 128
#define TNF 128
#define NSPLITF 4
#define NRANGE (NE / NSPLITF)   // 2048

// ---- refine geometry ----
#define RPB 8                   // flagged rows per block
#define NSR 8                   // refine n-splits (1024 cols each)

// ---- workspace layout (bytes) ----
#define WS_PM1  0               // float[NROWS*4]
#define WS_PM2  262144          // float[NROWS*4]
#define WS_PI1  524288          // int[NROWS*4]
#define WS_FIDX 786432          // int[NROWS]
#define WS_LIST 851968          // int[NROWS]
#define WS_CNT  917504          // int
#define WS_EH   1048576         // ushort[NE*DIM] = 8 MB   (dead after k_fastm)
#define WS_EL   9437184         // ushort[NE*DIM] = 8 MB
// refine partials overlay the (dead) EH region:
#define WS_RD   1048576         // float[NROWS*NSR] = 512 KB
#define WS_RN   1572864         // int[NROWS*NSR]   = 512 KB

typedef __bf16 bf16x8 __attribute__((ext_vector_type(8)));
typedef unsigned short u16x8 __attribute__((ext_vector_type(8)));
typedef float f32x4v __attribute__((ext_vector_type(4)));

__device__ __forceinline__ unsigned int bf16rne(float f) {
  unsigned int u = __float_as_uint(f);
  return (u + 0x7FFFu + ((u >> 16) & 1u)) >> 16;
}
__device__ __forceinline__ void split2(float f, unsigned short& h, unsigned short& l) {
  unsigned int hb = bf16rne(f);
  h = (unsigned short)hb;
  float rem = f - __uint_as_float(hb << 16);
  l = (unsigned short)bf16rne(rem);
}

// async 16B global -> LDS (linear dest: wave-uniform base + lane*16)
typedef __attribute__((address_space(1))) const void GV;
typedef __attribute__((address_space(3))) void LV;
__device__ __forceinline__ void gload16(const void* g, void* l) {
  __builtin_amdgcn_global_load_lds((GV*)g, (LV*)l, 16, 0, 0);
}

// ---------------- K0: elementwise bf16 hi/lo pre-split ----------------
__global__ void k_presplit(const float* __restrict__ src,
                           unsigned short* __restrict__ hi,
                           unsigned short* __restrict__ lo) {
  size_t i8 = (size_t)blockIdx.x * 256 + threadIdx.x;
  const float4* s4 = (const float4*)src;
  float4 a = s4[i8 * 2], b = s4[i8 * 2 + 1];
  unsigned short h[8], l[8];
  split2(a.x, h[0], l[0]); split2(a.y, h[1], l[1]);
  split2(a.z, h[2], l[2]); split2(a.w, h[3], l[3]);
  split2(b.x, h[4], l[4]); split2(b.y, h[5], l[5]);
  split2(b.z, h[6], l[6]); split2(b.w, h[7], l[7]);
  *(u16x8*)(hi + i8 * 8) = (u16x8){h[0],h[1],h[2],h[3],h[4],h[5],h[6],h[7]};
  *(u16x8*)(lo + i8 * 8) = (u16x8){l[0],l[1],l[2],l[3],l[4],l[5],l[6],l[7]};
}

// ---------------- K1: MFMA GEMM-max, dbuf + global_load_lds + swizzled LDS ----------------
// grid (NROWS/TMF, NSPLITF), block 512 = 8 waves (4m x 2n), wave tile 32x64.
// launch_bounds (512,2): VGPR cap 128 (r9's (512,4) capped at 64 -> massive spill).
__global__ __launch_bounds__(512, 2) void k_fastm(
    const unsigned short* __restrict__ zh, const unsigned short* __restrict__ zl,
    const unsigned short* __restrict__ eh, const unsigned short* __restrict__ el,
    float* __restrict__ pm1, float* __restrict__ pm2, int* __restrict__ pi1,
    int* __restrict__ counter) {
  __shared__ unsigned short buf[2][4][TMF][32];   // [dbuf][zh,zl,eh,el][row][k] = 64 KB
  __shared__ float redm1[TMF][2], redm2[TMF][2];
  __shared__ int   redi1[TMF][2];

  const int t    = threadIdx.x;
  const int lane = t & 63, w = t >> 6;
  const int wm   = w >> 1, wn = w & 1;
  const int lr   = lane & 15, lg = lane >> 4;
  const int mBase  = blockIdx.x * TMF;
  const int nBase0 = blockIdx.y * NRANGE;
  if (blockIdx.x == 0 && blockIdx.y == 0 && t == 0) *counter = 0;

  // staging lane map: wave w stages rows 16w..16w+15 of each tile
  const int srow = (w << 4) + (lane >> 2);            // local row
  const int sslot = (lane & 3) ^ ((srow >> 1) & 3);   // inverse-swizzled logical slot
  const size_t zrowoff = (size_t)(mBase + srow) * DIM + sslot * 8;

  float m1[8], m2[8]; int i1[8];
  #pragma unroll
  for (int s = 0; s < 8; ++s) { m1[s] = -FLT_MAX; m2[s] = -FLT_MAX; i1[s] = INT_MAX; }

  // prologue: stage step 0 into buffer 0
  {
    gload16(zh + zrowoff, &buf[0][0][w << 4][0]);
    gload16(zl + zrowoff, &buf[0][1][w << 4][0]);
    size_t eoff = (size_t)(nBase0 + srow) * DIM + sslot * 8;
    gload16(eh + eoff, &buf[0][2][w << 4][0]);
    gload16(el + eoff, &buf[0][3][w << 4][0]);
  }
  __syncthreads();

  int cur = 0;
  for (int nt = 0; nt < NRANGE / TNF; ++nt) {     // 16 n-tiles
    const int nB = nBase0 + nt * TNF;
    f32x4v acc[2][4];
    #pragma unroll
    for (int mi = 0; mi < 2; ++mi)
      #pragma unroll
      for (int nj = 0; nj < 4; ++nj) acc[mi][nj] = (f32x4v){0.f, 0.f, 0.f, 0.f};

    for (int ks = 0; ks < 16; ++ks) {             // 16 K-steps of 32
      // ---- stage next step into buf[cur^1] (async, hides under MFMA) ----
      int s = nt * 16 + ks;
      if (s + 1 < 256) {
        int s2 = s + 1, nt2 = s2 >> 4, ks2 = s2 & 15;
        size_t zo = zrowoff + ks2 * 32;
        size_t eo = (size_t)(nBase0 + nt2 * TNF + srow) * DIM + ks2 * 32 + sslot * 8;
        gload16(zh + zo, &buf[cur ^ 1][0][w << 4][0]);
        gload16(zl + zo, &buf[cur ^ 1][1][w << 4][0]);
        gload16(eh + eo, &buf[cur ^ 1][2][w << 4][0]);
        gload16(el + eo, &buf[cur ^ 1][3][w << 4][0]);
      }
      // ---- compute on buf[cur] (swizzled fragment reads) ----
      bf16x8 ah[2], al[2];
      #pragma unroll
      for (int mi = 0; mi < 2; ++mi) {
        int row = wm * 32 + mi * 16 + lr;
        int sl  = (lg ^ ((row >> 1) & 3)) * 8;
        ah[mi] = *(const bf16x8*)&buf[cur][0][row][sl];
        al[mi] = *(const bf16x8*)&buf[cur][1][row][sl];
      }
      #pragma unroll
      for (int nj = 0; nj < 4; ++nj) {
        int erow = wn * 64 + nj * 16 + lr;
        int esl  = (lg ^ ((erow >> 1) & 3)) * 8;
        bf16x8 bh = *(const bf16x8*)&buf[cur][2][erow][esl];
        bf16x8 bl = *(const bf16x8*)&buf[cur][3][erow][esl];
        #pragma unroll
        for (int mi = 0; mi < 2; ++mi) {
          acc[mi][nj] = __builtin_amdgcn_mfma_f32_16x16x32_bf16(ah[mi], bh, acc[mi][nj], 0, 0, 0);
          acc[mi][nj] = __builtin_amdgcn_mfma_f32_16x16x32_bf16(ah[mi], bl, acc[mi][nj], 0, 0, 0);
          acc[mi][nj] = __builtin_amdgcn_mfma_f32_16x16x32_bf16(al[mi], bh, acc[mi][nj], 0, 0, 0);
        }
      }
      __syncthreads();          // drains vmcnt (stage done); buf[cur] reads done
      cur ^= 1;
    }
    // fold into per-thread top-2 (n ascending in (nt,nj) -> first-index kept)
    #pragma unroll
    for (int nj = 0; nj < 4; ++nj) {
      int n = nB + wn * 64 + nj * 16 + lr;
      #pragma unroll
      for (int mi = 0; mi < 2; ++mi)
        #pragma unroll
        for (int r = 0; r < 4; ++r) {
          float v = acc[mi][nj][r];
          int s = mi * 4 + r;
          if (v > m1[s]) { m2[s] = m1[s]; m1[s] = v; i1[s] = n; }
          else if (v > m2[s]) m2[s] = v;
        }
    }
  }

  // butterfly top-2 merge across the 16 col-lanes
  #pragma unroll
  for (int off = 1; off <= 8; off <<= 1) {
    #pragma unroll
    for (int s = 0; s < 8; ++s) {
      float om1 = __shfl_xor(m1[s], off);
      float om2 = __shfl_xor(m2[s], off);
      int   oi  = __shfl_xor(i1[s], off);
      if (om1 > m1[s] || (om1 == m1[s] && oi < i1[s])) {
        m2[s] = fmaxf(m1[s], om2); m1[s] = om1; i1[s] = oi;
      } else {
        m2[s] = fmaxf(m2[s], om1);
      }
    }
  }
  if (lr == 0) {
    #pragma unroll
    for (int s = 0; s < 8; ++s) {
      int row = wm * 32 + (s >> 2) * 16 + lg * 4 + (s & 3);
      redm1[row][wn] = m1[s]; redm2[row][wn] = m2[s]; redi1[row][wn] = i1[s];
    }
  }
  __syncthreads();
  if (t < TMF) {
    float M1 = redm1[t][0], M2 = redm2[t][0]; int I1 = redi1[t][0];
    float a1 = redm1[t][1], a2 = redm2[t][1]; int ai = redi1[t][1];
    if (a1 > M1 || (a1 == M1 && ai < I1)) { M2 = fmaxf(M1, a2); M1 = a1; I1 = ai; }
    else M2 = fmaxf(M2, a1);
    size_t gm = (size_t)(mBase + t);
    pm1[gm * NSPLITF + blockIdx.y] = M1;
    pm2[gm * NSPLITF + blockIdx.y] = M2;
    pi1[gm * NSPLITF + blockIdx.y] = I1;
  }
}

// ---------------- K2: merge splits, compute A, flag near-ties ----------------
__global__ void k_merge(const float* __restrict__ z,
                        const float* __restrict__ pm1, const float* __restrict__ pm2,
                        const int* __restrict__ pi1,
                        int* __restrict__ fidx, int* __restrict__ list,
                        int* __restrict__ counter) {
  int m = blockIdx.x * 256 + threadIdx.x;
  float M1 = -FLT_MAX, M2 = -FLT_MAX; int I1 = INT_MAX;
  #pragma unroll
  for (int s = 0; s < NSPLITF; ++s) {
    float a1 = pm1[(size_t)m * NSPLITF + s], a2 = pm2[(size_t)m * NSPLITF + s];
    int   ai = pi1[(size_t)m * NSPLITF + s];
    if (a1 > M1 || (a1 == M1 && ai < I1)) { M2 = fmaxf(M1, a2); M1 = a1; I1 = ai; }
    else M2 = fmaxf(M2, a1);
  }
  double A = 0.0;
  const float4* zr = (const float4*)(z + (size_t)m * DIM);
  for (int q = 0; q < DIM / 4; ++q) {
    float4 v = zr[q];
    A += (double)v.x * v.x + (double)v.y * v.y + (double)v.z * v.z + (double)v.w * v.w;
  }
  float A32 = (float)A;
  float u   = (A32 > 511.8f) ? 6.1035156e-5f : 3.0517578e-5f;
  float tau = 0.75f * u + 3.5e-6f;
  fidx[m] = I1;
  if (M1 - M2 < tau) { int p = atomicAdd(counter, 1); list[p] = m; }
}

// ---------------- K3: exact npyv rescan v3: b128 LDS, 8 rows x 8 n-splits ----------------
// grid (NROWS/RPB, NSR), block 256 = rg(2) x cg(128); thread: 4 rows x 4 cols/tile
__global__ __launch_bounds__(256) void k_refine3(
    const float* __restrict__ z, const float* __restrict__ cb,
    const int* __restrict__ list, const int* __restrict__ counter,
    float* __restrict__ rd, int* __restrict__ rn) {
  __shared__ float est2[512][20];                 // [col][k-in-chunk], pad 20: 40 KB
  __shared__ __align__(16) float zs2[RPB][516];
  __shared__ double apart[RPB][16];
  __shared__ float Arow[RPB];
  __shared__ int mrow[RPB];
  __shared__ float rdm[RPB][128];
  __shared__ int rnm[RPB][128];

  const int cnt = *counter;
  const int gB = blockIdx.x * RPB;
  if (gB >= cnt) return;                          // uniform exit
  const int t = threadIdx.x;
  const int split = blockIdx.y;
  const int nBase0 = split * (NE / NSR);          // 1024-col range
  const int rg = t >> 7, cg = t & 127;

  if (t < RPB) mrow[t] = list[(gB + t < cnt) ? gB + t : cnt - 1];
  __syncthreads();
  #pragma unroll
  for (int i = 0; i < 4; ++i) {                   // stage 8 z rows
    int li = t + 256 * i; int r = li >> 7, q = li & 127;
    *(float4*)&zs2[r][q * 4] = *(const float4*)(z + (size_t)mrow[r] * DIM + q * 4);
  }
  __syncthreads();
  if (t < 128) {                                  // A per row (f64)
    int r = t >> 4, seg = t & 15;
    double s = 0.0;
    for (int k = seg * 32; k < seg * 32 + 32; ++k) { double v = zs2[r][k]; s += v * v; }
    apart[r][seg] = s;
  }
  __syncthreads();
  if (t < RPB) { double s = 0.0; for (int c2 = 0; c2 < 16; ++c2) s += apart[t][c2]; Arow[t] = (float)s; }
  __syncthreads();

  float bd[4] = {FLT_MAX, FLT_MAX, FLT_MAX, FLT_MAX};
  int   bn[4] = {INT_MAX, INT_MAX, INT_MAX, INT_MAX};

  for (int tile = 0; tile < 2; ++tile) {          // 2 x 512 cols
    const int colBase = nBase0 + tile * 512;
    float L[4][4][4];                             // [row][colj][npyv lane]
    #pragma unroll
    for (int r = 0; r < 4; ++r)
      #pragma unroll
      for (int cj = 0; cj < 4; ++cj)
        #pragma unroll
        for (int j = 0; j < 4; ++j) L[r][cj][j] = 0.0f;

    for (int kc = 0; kc < DIM; kc += 16) {        // 32 chunks of 16 k
      __syncthreads();
      // stage est2[col][0..15] = cb[colBase+col][kc..kc+15]: 2048 float4, 8/thread
      #pragma unroll
      for (int i = 0; i < 8; ++i) {
        int li = t + 256 * i; int col = li >> 2, q = li & 3;
        float4 v = *(const float4*)(cb + (size_t)(colBase + col) * DIM + kc + 4 * q);
        *(float4*)&est2[col][4 * q] = v;
      }
      __syncthreads();
      #pragma unroll
      for (int sub = 3; sub >= 0; --sub) {        // npyv within-chunk order 3,2,1,0
        float4 zv[4], ev[4];
        #pragma unroll
        for (int r = 0; r < 4; ++r)
          zv[r] = *(const float4*)&zs2[rg * 4 + r][kc + 4 * sub];   // broadcast b128
        #pragma unroll
        for (int cj = 0; cj < 4; ++cj)
          ev[cj] = *(const float4*)&est2[cg + 128 * cj][4 * sub];   // b128, 8 start banks
        #pragma unroll
        for (int r = 0; r < 4; ++r)
          #pragma unroll
          for (int cj = 0; cj < 4; ++cj) {
            L[r][cj][0] = __fadd_rn(L[r][cj][0], __fmul_rn(zv[r].x, ev[cj].x));
            L[r][cj][1] = __fadd_rn(L[r][cj][1], __fmul_rn(zv[r].y, ev[cj].y));
            L[r][cj][2] = __fadd_rn(L[r][cj][2], __fmul_rn(zv[r].z, ev[cj].z));
            L[r][cj][3] = __fadd_rn(L[r][cj][3], __fmul_rn(zv[r].w, ev[cj].w));
          }
      }
    }
    #pragma unroll
    for (int cj = 0; cj < 4; ++cj)
      #pragma unroll
      for (int r = 0; r < 4; ++r) {
        float G = __fadd_rn(__fadd_rn(L[r][cj][0], L[r][cj][1]),
                            __fadd_rn(L[r][cj][2], L[r][cj][3]));
        float d = __fsub_rn(Arow[rg * 4 + r], __fmul_rn(2.0f, G));
        int n = colBase + cg + 128 * cj;
        if (d < bd[r] || (d == bd[r] && n < bn[r])) { bd[r] = d; bn[r] = n; }
      }
  }
  __syncthreads();
  #pragma unroll
  for (int r = 0; r < 4; ++r) { rdm[rg*4+r][cg] = bd[r]; rnm[rg*4+r][cg] = bn[r]; }
  __syncthreads();
  if (t < RPB && gB + t < cnt) {
    float fb = FLT_MAX; int fn = INT_MAX;
    for (int c2 = 0; c2 < 128; ++c2) {
      float d = rdm[t][c2]; int n = rnm[t][c2];
      if (d < fb || (d == fb && n < fn)) { fb = d; fn = n; }
    }
    size_t i = (size_t)(gB + t);
    rd[i * NSR + split] = fb;
    rn[i * NSR + split] = fn;
  }
}

// ---------------- K3b: merge refine splits (lex-min d then n) ----------------
__global__ void k_fmerge(const int* __restrict__ list, const int* __restrict__ counter,
                         const float* __restrict__ rd, const int* __restrict__ rn,
                         int* __restrict__ fidx) {
  int i = blockIdx.x * 256 + threadIdx.x;
  if (i >= *counter) return;
  int m = list[i];
  float fb = FLT_MAX; int fn = INT_MAX;
  #pragma unroll
  for (int s = 0; s < NSR; ++s) {
    float d = rd[(size_t)i * NSR + s]; int n = rn[(size_t)i * NSR + s];
    if (d < fb || (d == fb && n < fn)) { fb = d; fn = n; }
  }
  fidx[m] = fn;
}

// ---------------- K4: gather z_q + index floats (fully rewrites d_out) ----------------
__global__ void k_gather(const float* __restrict__ cb, const int* __restrict__ fidx,
                         float* __restrict__ out) {
  __shared__ int idxs[32];
  const int t = threadIdx.x;
  const int mBase = blockIdx.x * 32;
  if (t < 32) {
    int id = fidx[mBase + t];
    idxs[t] = id;
    out[(size_t)NROWS * DIM + mBase + t] = (float)id;
  }
  __syncthreads();
  #pragma unroll
  for (int i = 0; i < 16; ++i) {
    int li = t + i * 256, r = li >> 7, q = li & 127;
    *(float4*)(out + (size_t)(mBase + r) * DIM + q * 4) =
        *(const float4*)(cb + (size_t)idxs[r] * DIM + q * 4);
  }
}

extern "C" void kernel_launch(void* const* d_in, const int* in_sizes, int n_in,
                              void* d_out, int out_size, void* d_ws, size_t ws_size,
                              hipStream_t stream) {
  const float* z  = (const float*)d_in[0];
  const float* cb = (const float*)d_in[1];
  float* out = (float*)d_out;
  char* ws = (char*)d_ws;
  float* pm1 = (float*)(ws + WS_PM1);
  float* pm2 = (float*)(ws + WS_PM2);
  int*   pi1 = (int*)(ws + WS_PI1);
  int*   fidx = (int*)(ws + WS_FIDX);
  int*   list = (int*)(ws + WS_LIST);
  int*   cnt  = (int*)(ws + WS_CNT);
  float* rdp  = (float*)(ws + WS_RD);   // overlays EH (dead after k_fastm)
  int*   rnp  = (int*)(ws + WS_RN);

  // z hi/lo pre-split lives in d_out; k_gather fully rewrites d_out afterward.
  unsigned short* zh = (unsigned short*)d_out;
  unsigned short* zl = zh + (size_t)NROWS * DIM;
  unsigned short* eh = (unsigned short*)(ws + WS_EH);
  unsigned short* el = (unsigned short*)(ws + WS_EL);

  hipLaunchKernelGGL(k_presplit, dim3(NROWS * DIM / (256 * 8)), dim3(256), 0, stream,
                     z, zh, zl);
  hipLaunchKernelGGL(k_presplit, dim3(NE * DIM / (256 * 8)), dim3(256), 0, stream,
                     cb, eh, el);
  hipLaunchKernelGGL(k_fastm,   dim3(NROWS / TMF, NSPLITF), dim3(512), 0, stream,
                     zh, zl, eh, el, pm1, pm2, pi1, cnt);
  hipLaunchKernelGGL(k_merge,   dim3(NROWS / 256), dim3(256), 0, stream,
                     z, pm1, pm2, pi1, fidx, list, cnt);
  hipLaunchKernelGGL(k_refine3, dim3(NROWS / RPB, NSR), dim3(256), 0, stream,
                     z, cb, list, cnt, rdp, rnp);
  hipLaunchKernelGGL(k_fmerge,  dim3(NROWS / 256), dim3(256), 0, stream,
                     list, cnt, rdp, rnp, fidx);
  hipLaunchKernelGGL(k_gather,  dim3(NROWS / 32), dim3(256), 0, stream,
                     cb, fidx, out);
}

// Round 11
// 951.536 us; speedup vs baseline: 2.2034x; 1.0338x over previous
//
#include <hip/hip_runtime.h>
#include <float.h>
#include <limits.h>

#define NROWS 16384
#define NE    8192
#define DIM   512

// ---- fast pass geometry ----
#define TMF 64
#define TNF 128
#define NSPLITF 4
#define NRANGE (NE / NSPLITF)   // 2048

// ---- refine geometry ----
#define RPB 8
#define NSR 8

// ---- workspace layout (bytes) ----
#define WS_PM1  0               // float[NROWS*4]
#define WS_PM2  262144          // float[NROWS*4]
#define WS_PI1  524288          // int[NROWS*4]
#define WS_FIDX 786432          // int[NROWS]
#define WS_LIST 851968          // int[NROWS]
#define WS_CNT  917504          // int
#define WS_EH   1048576         // ushort[NE*DIM] = 8 MB (dead after k_fastm)
#define WS_EL   9437184         // ushort[NE*DIM] = 8 MB
#define WS_RD   1048576         // float[NROWS*NSR] overlays EH
#define WS_RN   1572864         // int[NROWS*NSR]

typedef __bf16 bf16x8 __attribute__((ext_vector_type(8)));
typedef unsigned short u16x8 __attribute__((ext_vector_type(8)));
typedef float f32x4v __attribute__((ext_vector_type(4)));

__device__ __forceinline__ unsigned int bf16rne(float f) {
  unsigned int u = __float_as_uint(f);
  return (u + 0x7FFFu + ((u >> 16) & 1u)) >> 16;
}
__device__ __forceinline__ void split2(float f, unsigned short& h, unsigned short& l) {
  unsigned int hb = bf16rne(f);
  h = (unsigned short)hb;
  float rem = f - __uint_as_float(hb << 16);
  l = (unsigned short)bf16rne(rem);
}

typedef __attribute__((address_space(1))) const void GV;
typedef __attribute__((address_space(3))) void LV;
__device__ __forceinline__ void gload16(const void* g, void* l) {
  __builtin_amdgcn_global_load_lds((GV*)g, (LV*)l, 16, 0, 0);
}

// ---------------- K0: elementwise bf16 hi/lo pre-split ----------------
__global__ void k_presplit(const float* __restrict__ src,
                           unsigned short* __restrict__ hi,
                           unsigned short* __restrict__ lo) {
  size_t i8 = (size_t)blockIdx.x * 256 + threadIdx.x;
  const float4* s4 = (const float4*)src;
  float4 a = s4[i8 * 2], b = s4[i8 * 2 + 1];
  unsigned short h[8], l[8];
  split2(a.x, h[0], l[0]); split2(a.y, h[1], l[1]);
  split2(a.z, h[2], l[2]); split2(a.w, h[3], l[3]);
  split2(b.x, h[4], l[4]); split2(b.y, h[5], l[5]);
  split2(b.z, h[6], l[6]); split2(b.w, h[7], l[7]);
  *(u16x8*)(hi + i8 * 8) = (u16x8){h[0],h[1],h[2],h[3],h[4],h[5],h[6],h[7]};
  *(u16x8*)(lo + i8 * 8) = (u16x8){l[0],l[1],l[2],l[3],l[4],l[5],l[6],l[7]};
}

// ---------------- K1: MFMA GEMM-max; z single-buffer, e dbuf, 3 blocks/CU ----------------
// grid (NROWS/TMF, NSPLITF) = (256,4), block 256 = 4 waves (2m x 2n), wave tile 32x64.
// LDS 41.5 KB -> 3 blocks/CU.  Per step: a-frags -> barrier A -> async stage(z,e next)
// -> b-frags + 24 MFMA -> barrier B (drains).  cap = 256/arg2 = 128 >= demand.
__global__ __launch_bounds__(256, 2) void k_fastm(
    const unsigned short* __restrict__ zh, const unsigned short* __restrict__ zl,
    const unsigned short* __restrict__ eh, const unsigned short* __restrict__ el,
    float* __restrict__ pm1, float* __restrict__ pm2, int* __restrict__ pi1,
    int* __restrict__ counter) {
  __shared__ unsigned short zbuf[2][TMF][32];       // [zh,zl][row][k]   8 KB, single
  __shared__ unsigned short ebuf[2][2][TNF][32];    // [dbuf][eh,el]    32 KB
  __shared__ float redm1[TMF][2], redm2[TMF][2];
  __shared__ int   redi1[TMF][2];

  const int t    = threadIdx.x;
  const int lane = t & 63, w = t >> 6;
  const int wm   = w >> 1, wn = w & 1;
  const int lr   = lane & 15, lg = lane >> 4;
  const int mBase  = blockIdx.x * TMF;
  const int nBase0 = blockIdx.y * NRANGE;
  if (blockIdx.x == 0 && blockIdx.y == 0 && t == 0) *counter = 0;

  // staging lane maps (inverse-swizzled global source, linear LDS dest — rule #21)
  const int srz = (w << 4) + (lane >> 2);                 // z rows [0,64)
  const unsigned zbase = (unsigned)(mBase + srz) * DIM + (((lane & 3) ^ ((srz >> 1) & 3)) << 3);
  const int sre0 = (w << 5) + (lane >> 2);                // e rows j=0
  const int sre1 = sre0 + 16;                             // e rows j=1
  const unsigned ebase0 = (unsigned)(nBase0 + sre0) * DIM + (((lane & 3) ^ ((sre0 >> 1) & 3)) << 3);
  const unsigned ebase1 = (unsigned)(nBase0 + sre1) * DIM + (((lane & 3) ^ ((sre1 >> 1) & 3)) << 3);

  float m1[8], m2[8]; int i1[8];
  #pragma unroll
  for (int s = 0; s < 8; ++s) { m1[s] = -FLT_MAX; m2[s] = -FLT_MAX; i1[s] = INT_MAX; }

  // prologue: stage step 0
  gload16(zh + zbase, &zbuf[0][w << 4][0]);
  gload16(zl + zbase, &zbuf[1][w << 4][0]);
  gload16(eh + ebase0, &ebuf[0][0][w << 5][0]);
  gload16(eh + ebase1, &ebuf[0][0][(w << 5) + 16][0]);
  gload16(el + ebase0, &ebuf[0][1][w << 5][0]);
  gload16(el + ebase1, &ebuf[0][1][(w << 5) + 16][0]);
  __syncthreads();

  int cur = 0;
  for (int nt = 0; nt < NRANGE / TNF; ++nt) {     // 16 n-tiles
    const int nB = nBase0 + nt * TNF;
    f32x4v acc[2][4];
    #pragma unroll
    for (int mi = 0; mi < 2; ++mi)
      #pragma unroll
      for (int nj = 0; nj < 4; ++nj) acc[mi][nj] = (f32x4v){0.f, 0.f, 0.f, 0.f};

    for (int ks = 0; ks < 16; ++ks) {             // 16 K-steps of 32
      // ---- a-frags from zbuf (swizzled reads) ----
      bf16x8 ah[2], al[2];
      #pragma unroll
      for (int mi = 0; mi < 2; ++mi) {
        int row = wm * 32 + mi * 16 + lr;
        int sl  = (lg ^ ((row >> 1) & 3)) * 8;
        ah[mi] = *(const bf16x8*)&zbuf[0][row][sl];
        al[mi] = *(const bf16x8*)&zbuf[1][row][sl];
      }
      __syncthreads();   // A: all a-frag reads retired (lgkm drained); vmcnt already 0

      // ---- stage next step (async; hides under MFMA phase) ----
      int s = nt * 16 + ks;
      if (s + 1 < 256) {
        int s2 = s + 1;
        unsigned zo = (unsigned)((s2 & 15) << 5);
        unsigned vo = ((unsigned)(s2 >> 4) << 16) | zo;   // nt2*TNF*DIM + ks2*32
        gload16(zh + zbase + zo, &zbuf[0][w << 4][0]);
        gload16(zl + zbase + zo, &zbuf[1][w << 4][0]);
        gload16(eh + ebase0 + vo, &ebuf[cur ^ 1][0][w << 5][0]);
        gload16(eh + ebase1 + vo, &ebuf[cur ^ 1][0][(w << 5) + 16][0]);
        gload16(el + ebase0 + vo, &ebuf[cur ^ 1][1][w << 5][0]);
        gload16(el + ebase1 + vo, &ebuf[cur ^ 1][1][(w << 5) + 16][0]);
      }

      // ---- b-frags + MFMA from ebuf[cur] ----
      #pragma unroll
      for (int nj = 0; nj < 4; ++nj) {
        int erow = wn * 64 + nj * 16 + lr;
        int esl  = (lg ^ ((erow >> 1) & 3)) * 8;
        bf16x8 bh = *(const bf16x8*)&ebuf[cur][0][erow][esl];
        bf16x8 bl = *(const bf16x8*)&ebuf[cur][1][erow][esl];
        #pragma unroll
        for (int mi = 0; mi < 2; ++mi) {
          acc[mi][nj] = __builtin_amdgcn_mfma_f32_16x16x32_bf16(ah[mi], bh, acc[mi][nj], 0, 0, 0);
          acc[mi][nj] = __builtin_amdgcn_mfma_f32_16x16x32_bf16(ah[mi], bl, acc[mi][nj], 0, 0, 0);
          acc[mi][nj] = __builtin_amdgcn_mfma_f32_16x16x32_bf16(al[mi], bh, acc[mi][nj], 0, 0, 0);
        }
      }
      __syncthreads();   // B: drains vmcnt (stages done) + lgkm (b reads done)
      cur ^= 1;
    }
    // fold into per-thread top-2 (n ascending in (nt,nj) -> first-index kept)
    #pragma unroll
    for (int nj = 0; nj < 4; ++nj) {
      int n = nB + wn * 64 + nj * 16 + lr;
      #pragma unroll
      for (int mi = 0; mi < 2; ++mi)
        #pragma unroll
        for (int r = 0; r < 4; ++r) {
          float v = acc[mi][nj][r];
          int s = mi * 4 + r;
          if (v > m1[s]) { m2[s] = m1[s]; m1[s] = v; i1[s] = n; }
          else if (v > m2[s]) m2[s] = v;
        }
    }
  }

  // butterfly top-2 merge across the 16 col-lanes
  #pragma unroll
  for (int off = 1; off <= 8; off <<= 1) {
    #pragma unroll
    for (int s = 0; s < 8; ++s) {
      float om1 = __shfl_xor(m1[s], off);
      float om2 = __shfl_xor(m2[s], off);
      int   oi  = __shfl_xor(i1[s], off);
      if (om1 > m1[s] || (om1 == m1[s] && oi < i1[s])) {
        m2[s] = fmaxf(m1[s], om2); m1[s] = om1; i1[s] = oi;
      } else {
        m2[s] = fmaxf(m2[s], om1);
      }
    }
  }
  if (lr == 0) {
    #pragma unroll
    for (int s = 0; s < 8; ++s) {
      int row = wm * 32 + (s >> 2) * 16 + lg * 4 + (s & 3);
      redm1[row][wn] = m1[s]; redm2[row][wn] = m2[s]; redi1[row][wn] = i1[s];
    }
  }
  __syncthreads();
  if (t < TMF) {
    float M1 = redm1[t][0], M2 = redm2[t][0]; int I1 = redi1[t][0];
    float a1 = redm1[t][1], a2 = redm2[t][1]; int ai = redi1[t][1];
    if (a1 > M1 || (a1 == M1 && ai < I1)) { M2 = fmaxf(M1, a2); M1 = a1; I1 = ai; }
    else M2 = fmaxf(M2, a1);
    size_t gm = (size_t)(mBase + t);
    pm1[gm * NSPLITF + blockIdx.y] = M1;
    pm2[gm * NSPLITF + blockIdx.y] = M2;
    pi1[gm * NSPLITF + blockIdx.y] = I1;
  }
}

// ---------------- K2: merge splits, compute A, flag near-ties ----------------
__global__ void k_merge(const float* __restrict__ z,
                        const float* __restrict__ pm1, const float* __restrict__ pm2,
                        const int* __restrict__ pi1,
                        int* __restrict__ fidx, int* __restrict__ list,
                        int* __restrict__ counter) {
  int m = blockIdx.x * 256 + threadIdx.x;
  float M1 = -FLT_MAX, M2 = -FLT_MAX; int I1 = INT_MAX;
  #pragma unroll
  for (int s = 0; s < NSPLITF; ++s) {
    float a1 = pm1[(size_t)m * NSPLITF + s], a2 = pm2[(size_t)m * NSPLITF + s];
    int   ai = pi1[(size_t)m * NSPLITF + s];
    if (a1 > M1 || (a1 == M1 && ai < I1)) { M2 = fmaxf(M1, a2); M1 = a1; I1 = ai; }
    else M2 = fmaxf(M2, a1);
  }
  double A = 0.0;
  const float4* zr = (const float4*)(z + (size_t)m * DIM);
  for (int q = 0; q < DIM / 4; ++q) {
    float4 v = zr[q];
    A += (double)v.x * v.x + (double)v.y * v.y + (double)v.z * v.z + (double)v.w * v.w;
  }
  float A32 = (float)A;
  float u   = (A32 > 511.8f) ? 6.1035156e-5f : 3.0517578e-5f;
  float tau = 0.75f * u + 3.5e-6f;
  fidx[m] = I1;
  if (M1 - M2 < tau) { int p = atomicAdd(counter, 1); list[p] = m; }
}

// ---------------- K3: exact npyv rescan v3: b128 LDS, 8 rows x 8 n-splits ----------------
__global__ __launch_bounds__(256) void k_refine3(
    const float* __restrict__ z, const float* __restrict__ cb,
    const int* __restrict__ list, const int* __restrict__ counter,
    float* __restrict__ rd, int* __restrict__ rn) {
  __shared__ float est2[512][20];
  __shared__ __align__(16) float zs2[RPB][516];
  __shared__ double apart[RPB][16];
  __shared__ float Arow[RPB];
  __shared__ int mrow[RPB];
  __shared__ float rdm[RPB][128];
  __shared__ int rnm[RPB][128];

  const int cnt = *counter;
  const int gB = blockIdx.x * RPB;
  if (gB >= cnt) return;
  const int t = threadIdx.x;
  const int split = blockIdx.y;
  const int nBase0 = split * (NE / NSR);
  const int rg = t >> 7, cg = t & 127;

  if (t < RPB) mrow[t] = list[(gB + t < cnt) ? gB + t : cnt - 1];
  __syncthreads();
  #pragma unroll
  for (int i = 0; i < 4; ++i) {
    int li = t + 256 * i; int r = li >> 7, q = li & 127;
    *(float4*)&zs2[r][q * 4] = *(const float4*)(z + (size_t)mrow[r] * DIM + q * 4);
  }
  __syncthreads();
  if (t < 128) {
    int r = t >> 4, seg = t & 15;
    double s = 0.0;
    for (int k = seg * 32; k < seg * 32 + 32; ++k) { double v = zs2[r][k]; s += v * v; }
    apart[r][seg] = s;
  }
  __syncthreads();
  if (t < RPB) { double s = 0.0; for (int c2 = 0; c2 < 16; ++c2) s += apart[t][c2]; Arow[t] = (float)s; }
  __syncthreads();

  float bd[4] = {FLT_MAX, FLT_MAX, FLT_MAX, FLT_MAX};
  int   bn[4] = {INT_MAX, INT_MAX, INT_MAX, INT_MAX};

  for (int tile = 0; tile < 2; ++tile) {
    const int colBase = nBase0 + tile * 512;
    float L[4][4][4];
    #pragma unroll
    for (int r = 0; r < 4; ++r)
      #pragma unroll
      for (int cj = 0; cj < 4; ++cj)
        #pragma unroll
        for (int j = 0; j < 4; ++j) L[r][cj][j] = 0.0f;

    for (int kc = 0; kc < DIM; kc += 16) {
      __syncthreads();
      #pragma unroll
      for (int i = 0; i < 8; ++i) {
        int li = t + 256 * i; int col = li >> 2, q = li & 3;
        float4 v = *(const float4*)(cb + (size_t)(colBase + col) * DIM + kc + 4 * q);
        *(float4*)&est2[col][4 * q] = v;
      }
      __syncthreads();
      #pragma unroll
      for (int sub = 3; sub >= 0; --sub) {
        float4 zv[4], ev[4];
        #pragma unroll
        for (int r = 0; r < 4; ++r)
          zv[r] = *(const float4*)&zs2[rg * 4 + r][kc + 4 * sub];
        #pragma unroll
        for (int cj = 0; cj < 4; ++cj)
          ev[cj] = *(const float4*)&est2[cg + 128 * cj][4 * sub];
        #pragma unroll
        for (int r = 0; r < 4; ++r)
          #pragma unroll
          for (int cj = 0; cj < 4; ++cj) {
            L[r][cj][0] = __fadd_rn(L[r][cj][0], __fmul_rn(zv[r].x, ev[cj].x));
            L[r][cj][1] = __fadd_rn(L[r][cj][1], __fmul_rn(zv[r].y, ev[cj].y));
            L[r][cj][2] = __fadd_rn(L[r][cj][2], __fmul_rn(zv[r].z, ev[cj].z));
            L[r][cj][3] = __fadd_rn(L[r][cj][3], __fmul_rn(zv[r].w, ev[cj].w));
          }
      }
    }
    #pragma unroll
    for (int cj = 0; cj < 4; ++cj)
      #pragma unroll
      for (int r = 0; r < 4; ++r) {
        float G = __fadd_rn(__fadd_rn(L[r][cj][0], L[r][cj][1]),
                            __fadd_rn(L[r][cj][2], L[r][cj][3]));
        float d = __fsub_rn(Arow[rg * 4 + r], __fmul_rn(2.0f, G));
        int n = colBase + cg + 128 * cj;
        if (d < bd[r] || (d == bd[r] && n < bn[r])) { bd[r] = d; bn[r] = n; }
      }
  }
  __syncthreads();
  #pragma unroll
  for (int r = 0; r < 4; ++r) { rdm[rg*4+r][cg] = bd[r]; rnm[rg*4+r][cg] = bn[r]; }
  __syncthreads();
  if (t < RPB && gB + t < cnt) {
    float fb = FLT_MAX; int fn = INT_MAX;
    for (int c2 = 0; c2 < 128; ++c2) {
      float d = rdm[t][c2]; int n = rnm[t][c2];
      if (d < fb || (d == fb && n < fn)) { fb = d; fn = n; }
    }
    size_t i = (size_t)(gB + t);
    rd[i * NSR + split] = fb;
    rn[i * NSR + split] = fn;
  }
}

// ---------------- K3b: merge refine splits ----------------
__global__ void k_fmerge(const int* __restrict__ list, const int* __restrict__ counter,
                         const float* __restrict__ rd, const int* __restrict__ rn,
                         int* __restrict__ fidx) {
  int i = blockIdx.x * 256 + threadIdx.x;
  if (i >= *counter) return;
  int m = list[i];
  float fb = FLT_MAX; int fn = INT_MAX;
  #pragma unroll
  for (int s = 0; s < NSR; ++s) {
    float d = rd[(size_t)i * NSR + s]; int n = rn[(size_t)i * NSR + s];
    if (d < fb || (d == fb && n < fn)) { fb = d; fn = n; }
  }
  fidx[m] = fn;
}

// ---------------- K4: gather z_q + index floats (fully rewrites d_out) ----------------
__global__ void k_gather(const float* __restrict__ cb, const int* __restrict__ fidx,
                         float* __restrict__ out) {
  __shared__ int idxs[32];
  const int t = threadIdx.x;
  const int mBase = blockIdx.x * 32;
  if (t < 32) {
    int id = fidx[mBase + t];
    idxs[t] = id;
    out[(size_t)NROWS * DIM + mBase + t] = (float)id;
  }
  __syncthreads();
  #pragma unroll
  for (int i = 0; i < 16; ++i) {
    int li = t + i * 256, r = li >> 7, q = li & 127;
    *(float4*)(out + (size_t)(mBase + r) * DIM + q * 4) =
        *(const float4*)(cb + (size_t)idxs[r] * DIM + q * 4);
  }
}

extern "C" void kernel_launch(void* const* d_in, const int* in_sizes, int n_in,
                              void* d_out, int out_size, void* d_ws, size_t ws_size,
                              hipStream_t stream) {
  const float* z  = (const float*)d_in[0];
  const float* cb = (const float*)d_in[1];
  float* out = (float*)d_out;
  char* ws = (char*)d_ws;
  float* pm1 = (float*)(ws + WS_PM1);
  float* pm2 = (float*)(ws + WS_PM2);
  int*   pi1 = (int*)(ws + WS_PI1);
  int*   fidx = (int*)(ws + WS_FIDX);
  int*   list = (int*)(ws + WS_LIST);
  int*   cnt  = (int*)(ws + WS_CNT);
  float* rdp  = (float*)(ws + WS_RD);
  int*   rnp  = (int*)(ws + WS_RN);

  // z hi/lo pre-split lives in d_out; k_gather fully rewrites d_out afterward.
  unsigned short* zh = (unsigned short*)d_out;
  unsigned short* zl = zh + (size_t)NROWS * DIM;
  unsigned short* eh = (unsigned short*)(ws + WS_EH);
  unsigned short* el = (unsigned short*)(ws + WS_EL);

  hipLaunchKernelGGL(k_presplit, dim3(NROWS * DIM / (256 * 8)), dim3(256), 0, stream,
                     z, zh, zl);
  hipLaunchKernelGGL(k_presplit, dim3(NE * DIM / (256 * 8)), dim3(256), 0, stream,
                     cb, eh, el);
  hipLaunchKernelGGL(k_fastm,   dim3(NROWS / TMF, NSPLITF), dim3(256), 0, stream,
                     zh, zl, eh, el, pm1, pm2, pi1, cnt);
  hipLaunchKernelGGL(k_merge,   dim3(NROWS / 256), dim3(256), 0, stream,
                     z, pm1, pm2, pi1, fidx, list, cnt);
  hipLaunchKernelGGL(k_refine3, dim3(NROWS / RPB, NSR), dim3(256), 0, stream,
                     z, cb, list, cnt, rdp, rnp);
  hipLaunchKernelGGL(k_fmerge,  dim3(NROWS / 256), dim3(256), 0, stream,
                     list, cnt, rdp, rnp, fidx);
  hipLaunchKernelGGL(k_gather,  dim3(NROWS / 32), dim3(256), 0, stream,
                     cb, fidx, out);
}